// Round 1
// baseline (191.824 us; speedup 1.0000x reference)
//
#include <hip/hip_runtime.h>
#include <stdint.h>

using u16 = unsigned short;
using u32 = unsigned int;

typedef float f32x4 __attribute__((ext_vector_type(4)));
typedef __bf16 bf16x8 __attribute__((ext_vector_type(8)));

#define DEV static __device__ __forceinline__

// f32 -> bf16 round-to-nearest-even
DEV u16 f2bf(float f) {
  u32 u = __float_as_uint(f);
  u += 0x7FFFu + ((u >> 16) & 1u);
  return (u16)(u >> 16);
}

// async global->LDS, 16B per lane. LDS dest = wave-uniform base + lane*16.
DEV void gld16(const void* g, void* l) {
  __builtin_amdgcn_global_load_lds((__attribute__((address_space(1))) void*)g,
                                   (__attribute__((address_space(3))) void*)l,
                                   16, 0, 0);
}

// ---------------------------------------------------------------- converts
__global__ void k_cvt_x(const float* __restrict__ x, u16* __restrict__ xb) {
  int i = (blockIdx.x * 256 + threadIdx.x) * 8;
  float4 a = *(const float4*)&x[i];
  float4 b = *(const float4*)&x[i + 4];
  __align__(16) u16 o[8];
  o[0] = f2bf(a.x); o[1] = f2bf(a.y); o[2] = f2bf(a.z); o[3] = f2bf(a.w);
  o[4] = f2bf(b.x); o[5] = f2bf(b.y); o[6] = f2bf(b.z); o[7] = f2bf(b.w);
  *(uint4*)&xb[i] = *(const uint4*)o;
}

// convert f32 [K=1024][N=1024] weight -> bf16 transposed [N][K]
__global__ void k_cvt_w(const float* __restrict__ w0, const float* __restrict__ w1,
                        const float* __restrict__ w2, const float* __restrict__ w3,
                        u16* __restrict__ t0, u16* __restrict__ t1,
                        u16* __restrict__ t2, u16* __restrict__ t3) {
  const float* w = blockIdx.z == 0 ? w0 : blockIdx.z == 1 ? w1 : blockIdx.z == 2 ? w2 : w3;
  u16* wt       = blockIdx.z == 0 ? t0 : blockIdx.z == 1 ? t1 : blockIdx.z == 2 ? t2 : t3;
  __shared__ __align__(16) float tile[64][68];
  const int tid = threadIdx.x;
  const int k0 = blockIdx.x * 64, n0 = blockIdx.y * 64;
#pragma unroll
  for (int i = 0; i < 4; ++i) {
    int c = tid + i * 256;          // 1024 float4 chunks
    int kr = c >> 4, col = (c & 15) * 4;
    *(float4*)&tile[kr][col] = *(const float4*)&w[(size_t)(k0 + kr) * 1024 + n0 + col];
  }
  __syncthreads();
#pragma unroll
  for (int i = 0; i < 2; ++i) {
    int c = tid + i * 256;          // 512 8xu16 chunks
    int nr = c >> 3, kc = (c & 7) * 8;
    __align__(16) u16 o[8];
#pragma unroll
    for (int j = 0; j < 8; ++j) o[j] = f2bf(tile[kc + j][nr]);
    *(uint4*)&wt[(size_t)(n0 + nr) * 1024 + k0 + kc] = *(const uint4*)o;
  }
}

// ---------------------------------------------------------------- GEMM core
// C[128x128] tile = A[m0..+128][K=1024] * Bt[n0..+128][K=1024]^T, bf16 MFMA.
// LDS tiles [128][32] bf16 (64B rows, 4x16B blocks), XOR-swizzled via
// pre-swizzled global source: block' = block ^ (row&3) ^ ((row>>2)&3).
DEV void gemm_mainloop(const u16* __restrict__ A, const u16* __restrict__ Bt,
                       int m0, int n0, u16* Asb, u16* Bsb, f32x4 (&acc)[4][4]) {
  const int tid = threadIdx.x;
  const int lane = tid & 63;
  const int wv = tid >> 6;
  const int wm = (wv >> 1) * 64, wn = (wv & 1) * 64;

#pragma unroll
  for (int i = 0; i < 4; ++i)
#pragma unroll
    for (int j = 0; j < 4; ++j) {
      f32x4 z = {0.f, 0.f, 0.f, 0.f};
      acc[i][j] = z;
    }

  const int c0 = wv * 64 + lane, c1 = c0 + 256;
  const int r0 = c0 >> 2, r1 = c1 >> 2;
  const int b0 = (c0 & 3) ^ (r0 & 3) ^ ((r0 >> 2) & 3);
  const int b1 = (c1 & 3) ^ (r1 & 3) ^ ((r1 >> 2) & 3);
  const u16* ga0 = A + (size_t)(m0 + r0) * 1024 + b0 * 8;
  const u16* ga1 = A + (size_t)(m0 + r1) * 1024 + b1 * 8;
  const u16* gb0 = Bt + (size_t)(n0 + r0) * 1024 + b0 * 8;
  const u16* gb1 = Bt + (size_t)(n0 + r1) * 1024 + b1 * 8;
  u16* la0 = Asb + (wv * 64) * 8;
  u16* la1 = Asb + (wv * 64 + 256) * 8;
  u16* lb0 = Bsb + (wv * 64) * 8;
  u16* lb1 = Bsb + (wv * 64 + 256) * 8;

  int aoff[4], boff[4];
#pragma unroll
  for (int f = 0; f < 4; ++f) {
    int ra = wm + f * 16 + (lane & 15);
    aoff[f] = ra * 32 + (((lane >> 4) ^ (ra & 3) ^ ((ra >> 2) & 3)) * 8);
    int rb = wn + f * 16 + (lane & 15);
    boff[f] = rb * 32 + (((lane >> 4) ^ (rb & 3) ^ ((rb >> 2) & 3)) * 8);
  }

  for (int kt = 0; kt < 32; ++kt) {
    const int k0 = kt * 32;
    gld16(ga0 + k0, la0);
    gld16(ga1 + k0, la1);
    gld16(gb0 + k0, lb0);
    gld16(gb1 + k0, lb1);
    __syncthreads();
    bf16x8 af[4], bfv[4];
#pragma unroll
    for (int f = 0; f < 4; ++f) af[f] = *(const bf16x8*)&Asb[aoff[f]];
#pragma unroll
    for (int f = 0; f < 4; ++f) bfv[f] = *(const bf16x8*)&Bsb[boff[f]];
#pragma unroll
    for (int i = 0; i < 4; ++i)
#pragma unroll
      for (int j = 0; j < 4; ++j)
        acc[i][j] = __builtin_amdgcn_mfma_f32_16x16x32_bf16(af[i], bfv[j], acc[i][j], 0, 0, 0);
    __syncthreads();
  }
}

// fused QKV projection: X[4096][1024]bf16 * Wt[1024][1024] -> Q/K/V [32][2048][64]bf16
__global__ __launch_bounds__(256) void k_gemm_qkv(
    const u16* __restrict__ X, const u16* __restrict__ Wq, const u16* __restrict__ Wk,
    const u16* __restrict__ Wv, u16* __restrict__ Q, u16* __restrict__ K,
    u16* __restrict__ V) {
  __shared__ __align__(16) u16 Asb[128 * 32];
  __shared__ __align__(16) u16 Bsb[128 * 32];
  const int nb = blockIdx.x, mb = blockIdx.y;
  const int proj = nb >> 3, n0 = (nb & 7) * 128;
  const u16* W = proj == 0 ? Wq : proj == 1 ? Wk : Wv;
  u16* Dst = proj == 0 ? Q : proj == 1 ? K : V;
  const float scl = proj == 0 ? 0.125f : 1.0f;  // fold 1/sqrt(64) into Q
  f32x4 acc[4][4];
  gemm_mainloop(X, W, mb * 128, n0, Asb, Bsb, acc);
  const int lane = threadIdx.x & 63, wv = threadIdx.x >> 6;
  const int wm = (wv >> 1) * 64, wn = (wv & 1) * 64;
#pragma unroll
  for (int i = 0; i < 4; ++i)
#pragma unroll
    for (int j = 0; j < 4; ++j)
#pragma unroll
      for (int r = 0; r < 4; ++r) {
        int m = mb * 128 + wm + i * 16 + (lane >> 4) * 4 + r;   // global row (b*2048+s)
        int n = n0 + wn + j * 16 + (lane & 15);                 // 0..1023
        int b = m >> 11, s = m & 2047, h = n >> 6, d = n & 63;
        Dst[(size_t)((b * 16 + h) * 2048 + s) * 64 + d] = f2bf(acc[i][j][r] * scl);
      }
}

// output projection: AO[4096][1024]bf16 * WOt -> f32 out [4096][1024]
__global__ __launch_bounds__(256) void k_gemm_out(
    const u16* __restrict__ A, const u16* __restrict__ Wt, float* __restrict__ Out) {
  __shared__ __align__(16) u16 Asb[128 * 32];
  __shared__ __align__(16) u16 Bsb[128 * 32];
  const int nb = blockIdx.x, mb = blockIdx.y;
  f32x4 acc[4][4];
  gemm_mainloop(A, Wt, mb * 128, nb * 128, Asb, Bsb, acc);
  const int lane = threadIdx.x & 63, wv = threadIdx.x >> 6;
  const int wm = (wv >> 1) * 64, wn = (wv & 1) * 64;
#pragma unroll
  for (int i = 0; i < 4; ++i)
#pragma unroll
    for (int j = 0; j < 4; ++j)
#pragma unroll
      for (int r = 0; r < 4; ++r) {
        int m = mb * 128 + wm + i * 16 + (lane >> 4) * 4 + r;
        int n = nb * 128 + wn + j * 16 + (lane & 15);
        Out[(size_t)m * 1024 + n] = acc[i][j][r];
      }
}

// ---------------------------------------------------------------- V transpose
// V [32][2048][64] -> Vt [32][64][2048]
__global__ void k_transpose_v(const u16* __restrict__ V, u16* __restrict__ Vt) {
  __shared__ __align__(16) u16 t[64][80];
  const int bh = blockIdx.y, s0 = blockIdx.x * 64;
  const int tid = threadIdx.x;
#pragma unroll
  for (int i = 0; i < 2; ++i) {
    int c = tid + i * 256;
    int sr = c >> 3, dc = (c & 7) * 8;
    *(uint4*)&t[sr][dc] = *(const uint4*)&V[((size_t)bh * 2048 + s0 + sr) * 64 + dc];
  }
  __syncthreads();
#pragma unroll
  for (int i = 0; i < 2; ++i) {
    int c = tid + i * 256;
    int dr = c >> 3, sc = (c & 7) * 8;
    __align__(16) u16 o[8];
#pragma unroll
    for (int j = 0; j < 8; ++j) o[j] = t[sc + j][dr];
    *(uint4*)&Vt[((size_t)bh * 64 + dr) * 2048 + s0 + sc] = *(const uint4*)o;
  }
}

// ---------------------------------------------------------------- attention
// per block: one (b,h), 128 q rows; 4 waves x 32 rows; KVBLK=64, causal.
__global__ __launch_bounds__(256) void k_attn(
    const u16* __restrict__ Qg, const u16* __restrict__ Kg,
    const u16* __restrict__ Vtg, u16* __restrict__ Og) {
  __shared__ __align__(16) u16 Ks[64 * 64];
  __shared__ __align__(16) u16 Vs[64 * 64];
  __shared__ __align__(16) u16 Ps[4][32 * 64];
  const int tid = threadIdx.x, lane = tid & 63, wv = tid >> 6;
  const int qt = blockIdx.x, bh = blockIdx.y;
  const int q0 = qt * 128;
  const u16* Qb = Qg + (size_t)bh * 2048 * 64;
  const u16* Kb = Kg + (size_t)bh * 2048 * 64;
  const u16* Vb = Vtg + (size_t)bh * 64 * 2048;

  // Q fragments in registers (scale already folded in)
  bf16x8 qf[2][2];
#pragma unroll
  for (int rf = 0; rf < 2; ++rf)
#pragma unroll
    for (int kf = 0; kf < 2; ++kf)
      qf[rf][kf] = *(const bf16x8*)&Qb[(size_t)(q0 + wv * 32 + rf * 16 + (lane & 15)) * 64 +
                                       kf * 32 + (lane >> 4) * 8];

  f32x4 ao[2][4];
  float m_run[2][4], l_run[2][4];
#pragma unroll
  for (int rf = 0; rf < 2; ++rf) {
#pragma unroll
    for (int df = 0; df < 4; ++df) {
      f32x4 z = {0.f, 0.f, 0.f, 0.f};
      ao[rf][df] = z;
    }
#pragma unroll
    for (int r = 0; r < 4; ++r) { m_run[rf][r] = -1e30f; l_run[rf][r] = 0.f; }
  }

  // staging geometry: 512 chunks of 16B per 64x64 bf16 tile (128B rows, 8 blocks)
  const int c0 = wv * 64 + lane, c1 = c0 + 256;
  const int r0 = c0 >> 3, r1 = c1 >> 3;
  const int e0 = ((c0 & 7) ^ (r0 & 7)) * 8;
  const int e1 = ((c1 & 7) ^ (r1 & 7)) * 8;
  u16* lk0 = Ks + wv * 512;
  u16* lk1 = Ks + wv * 512 + 2048;
  u16* lv0 = Vs + wv * 512;
  u16* lv1 = Vs + wv * 512 + 2048;

  const int ntiles = q0 / 64 + 2;  // causal: kv0 <= q0+127
  for (int t = 0; t < ntiles; ++t) {
    const int kv0 = t * 64;
    gld16(Kb + (size_t)(kv0 + r0) * 64 + e0, lk0);
    gld16(Kb + (size_t)(kv0 + r1) * 64 + e1, lk1);
    gld16(Vb + (size_t)r0 * 2048 + kv0 + e0, lv0);
    gld16(Vb + (size_t)r1 * 2048 + kv0 + e1, lv1);
    __syncthreads();

    // QK^T
    bf16x8 kfr[4][2];
#pragma unroll
    for (int cf = 0; cf < 4; ++cf)
#pragma unroll
      for (int kf = 0; kf < 2; ++kf) {
        int row = cf * 16 + (lane & 15);
        int blk = ((kf * 4 + (lane >> 4)) ^ (row & 7)) * 8;
        kfr[cf][kf] = *(const bf16x8*)&Ks[row * 64 + blk];
      }
    f32x4 sc[2][4];
#pragma unroll
    for (int rf = 0; rf < 2; ++rf)
#pragma unroll
      for (int cf = 0; cf < 4; ++cf) {
        f32x4 z = {0.f, 0.f, 0.f, 0.f};
        sc[rf][cf] = z;
#pragma unroll
        for (int kf = 0; kf < 2; ++kf)
          sc[rf][cf] = __builtin_amdgcn_mfma_f32_16x16x32_bf16(qf[rf][kf], kfr[cf][kf],
                                                               sc[rf][cf], 0, 0, 0);
      }

    // causal mask (only needed for last two tiles)
    if (kv0 + 63 > q0) {
#pragma unroll
      for (int rf = 0; rf < 2; ++rf)
#pragma unroll
        for (int cf = 0; cf < 4; ++cf)
#pragma unroll
          for (int r = 0; r < 4; ++r) {
            int qq = q0 + wv * 32 + rf * 16 + (lane >> 4) * 4 + r;
            int kk = kv0 + cf * 16 + (lane & 15);
            if (kk > qq) sc[rf][cf][r] = -1e30f;
          }
    }

    // online softmax per 16-row fragment (row lives in 16 lanes: shfl widths 1..8)
#pragma unroll
    for (int rf = 0; rf < 2; ++rf) {
      float mnew[4], sclf[4], ps[4];
#pragma unroll
      for (int r = 0; r < 4; ++r) {
        float mx = fmaxf(fmaxf(sc[rf][0][r], sc[rf][1][r]), fmaxf(sc[rf][2][r], sc[rf][3][r]));
        mx = fmaxf(mx, __shfl_xor(mx, 1));
        mx = fmaxf(mx, __shfl_xor(mx, 2));
        mx = fmaxf(mx, __shfl_xor(mx, 4));
        mx = fmaxf(mx, __shfl_xor(mx, 8));
        mnew[r] = fmaxf(m_run[rf][r], mx);
        sclf[r] = __expf(m_run[rf][r] - mnew[r]);
        m_run[rf][r] = mnew[r];
        ps[r] = 0.f;
      }
#pragma unroll
      for (int cf = 0; cf < 4; ++cf)
#pragma unroll
        for (int r = 0; r < 4; ++r) {
          float p = __expf(sc[rf][cf][r] - mnew[r]);
          sc[rf][cf][r] = p;
          ps[r] += p;
        }
#pragma unroll
      for (int r = 0; r < 4; ++r) {
        ps[r] += __shfl_xor(ps[r], 1);
        ps[r] += __shfl_xor(ps[r], 2);
        ps[r] += __shfl_xor(ps[r], 4);
        ps[r] += __shfl_xor(ps[r], 8);
        l_run[rf][r] = l_run[rf][r] * sclf[r] + ps[r];
      }
#pragma unroll
      for (int df = 0; df < 4; ++df)
#pragma unroll
        for (int r = 0; r < 4; ++r) ao[rf][df][r] *= sclf[r];
      // P -> bf16 -> per-wave swizzled LDS buffer
#pragma unroll
      for (int cf = 0; cf < 4; ++cf)
#pragma unroll
        for (int r = 0; r < 4; ++r) {
          int rl = rf * 16 + (lane >> 4) * 4 + r;
          int col = cf * 16 + (lane & 15);
          Ps[wv][rl * 64 + (col ^ ((rl & 7) << 3))] = f2bf(sc[rf][cf][r]);
        }
    }
    asm volatile("s_waitcnt lgkmcnt(0)" ::: "memory");

    // PV
    bf16x8 pf[2][2], vfr[4][2];
#pragma unroll
    for (int rf = 0; rf < 2; ++rf)
#pragma unroll
      for (int k2 = 0; k2 < 2; ++k2) {
        int row = rf * 16 + (lane & 15);
        pf[rf][k2] = *(const bf16x8*)&Ps[wv][row * 64 +
                       ((k2 * 32 + (lane >> 4) * 8) ^ ((row & 7) << 3))];
      }
#pragma unroll
    for (int df = 0; df < 4; ++df)
#pragma unroll
      for (int k2 = 0; k2 < 2; ++k2) {
        int row = df * 16 + (lane & 15);
        int blk = ((k2 * 4 + (lane >> 4)) ^ (row & 7)) * 8;
        vfr[df][k2] = *(const bf16x8*)&Vs[row * 64 + blk];
      }
#pragma unroll
    for (int rf = 0; rf < 2; ++rf)
#pragma unroll
      for (int df = 0; df < 4; ++df)
#pragma unroll
        for (int k2 = 0; k2 < 2; ++k2)
          ao[rf][df] = __builtin_amdgcn_mfma_f32_16x16x32_bf16(pf[rf][k2], vfr[df][k2],
                                                               ao[rf][df], 0, 0, 0);
    __syncthreads();
  }

  // epilogue: write [B][S][H*64] bf16 for the output projection
  const int b = bh >> 4, h = bh & 15;
#pragma unroll
  for (int rf = 0; rf < 2; ++rf)
#pragma unroll
    for (int df = 0; df < 4; ++df)
#pragma unroll
      for (int r = 0; r < 4; ++r) {
        int s = q0 + wv * 32 + rf * 16 + (lane >> 4) * 4 + r;
        int d = df * 16 + (lane & 15);
        float v = ao[rf][df][r] / l_run[rf][r];
        Og[((size_t)(b * 2048 + s)) * 1024 + h * 64 + d] = f2bf(v);
      }
}

// ---------------------------------------------------------------- launch
extern "C" void kernel_launch(void* const* d_in, const int* in_sizes, int n_in,
                              void* d_out, int out_size, void* d_ws, size_t ws_size,
                              hipStream_t stream) {
  const float* x = (const float*)d_in[0];
  // d_in[1] = causal mask (known layout; not needed on device)
  const float* wq = (const float*)d_in[2];
  const float* wk = (const float*)d_in[3];
  const float* wv = (const float*)d_in[4];
  const float* wo = (const float*)d_in[5];

  char* ws = (char*)d_ws;
  u16* xb  = (u16*)(ws);                                   // 8 MiB  x bf16 [4096][1024]
  u16* wqt = (u16*)(ws + 8388608);                         // 2 MiB each, [N][K] bf16
  u16* wkt = (u16*)(ws + 8388608 + 2097152);
  u16* wvt = (u16*)(ws + 8388608 + 2 * 2097152);
  u16* wot = (u16*)(ws + 8388608 + 3 * 2097152);
  u16* qb  = (u16*)(ws + 16777216);                        // [32][2048][64] bf16
  u16* kb  = (u16*)(ws + 16777216 + 8388608);
  u16* vb  = (u16*)(ws + 16777216 + 2 * 8388608);
  u16* vt  = (u16*)(ws + 16777216 + 3 * 8388608);          // [32][64][2048]
  u16* ao  = (u16*)(ws + 16777216 + 4 * 8388608);          // [4096][1024] bf16

  k_cvt_x<<<dim3(2048), dim3(256), 0, stream>>>(x, xb);
  k_cvt_w<<<dim3(16, 16, 4), dim3(256), 0, stream>>>(wq, wk, wv, wo, wqt, wkt, wvt, wot);
  k_gemm_qkv<<<dim3(24, 32), dim3(256), 0, stream>>>(xb, wqt, wkt, wvt, qb, kb, vb);
  k_transpose_v<<<dim3(32, 32), dim3(256), 0, stream>>>(vb, vt);
  k_attn<<<dim3(16, 32), dim3(256), 0, stream>>>(qb, kb, vt, ao);
  k_gemm_out<<<dim3(8, 32), dim3(256), 0, stream>>>(ao, wot, (float*)d_out);
}

// Round 2
// 150.143 us; speedup vs baseline: 1.2776x; 1.2776x over previous
//
#include <hip/hip_runtime.h>
#include <stdint.h>

using u16 = unsigned short;
using u32 = unsigned int;

typedef float f32x4 __attribute__((ext_vector_type(4)));
typedef __bf16 bf16x8 __attribute__((ext_vector_type(8)));

#define DEV static __device__ __forceinline__

// f32 -> bf16 round-to-nearest-even
DEV u16 f2bf(float f) {
  u32 u = __float_as_uint(f);
  u += 0x7FFFu + ((u >> 16) & 1u);
  return (u16)(u >> 16);
}

// async global->LDS, 16B per lane. LDS dest = wave-uniform base + lane*16.
DEV void gld16(const void* g, void* l) {
  __builtin_amdgcn_global_load_lds((__attribute__((address_space(1))) void*)g,
                                   (__attribute__((address_space(3))) void*)l,
                                   16, 0, 0);
}

// ---------------------------------------------------------------- converts
__global__ void k_cvt_x(const float* __restrict__ x, u16* __restrict__ xb) {
  int i = (blockIdx.x * 256 + threadIdx.x) * 8;
  float4 a = *(const float4*)&x[i];
  float4 b = *(const float4*)&x[i + 4];
  __align__(16) u16 o[8];
  o[0] = f2bf(a.x); o[1] = f2bf(a.y); o[2] = f2bf(a.z); o[3] = f2bf(a.w);
  o[4] = f2bf(b.x); o[5] = f2bf(b.y); o[6] = f2bf(b.z); o[7] = f2bf(b.w);
  *(uint4*)&xb[i] = *(const uint4*)o;
}

// convert f32 [K=1024][N=1024] weight -> bf16 transposed [N][K]
__global__ void k_cvt_w(const float* __restrict__ w0, const float* __restrict__ w1,
                        const float* __restrict__ w2, const float* __restrict__ w3,
                        u16* __restrict__ t0, u16* __restrict__ t1,
                        u16* __restrict__ t2, u16* __restrict__ t3) {
  const float* w = blockIdx.z == 0 ? w0 : blockIdx.z == 1 ? w1 : blockIdx.z == 2 ? w2 : w3;
  u16* wt       = blockIdx.z == 0 ? t0 : blockIdx.z == 1 ? t1 : blockIdx.z == 2 ? t2 : t3;
  __shared__ __align__(16) float tile[64][68];
  const int tid = threadIdx.x;
  const int k0 = blockIdx.x * 64, n0 = blockIdx.y * 64;
#pragma unroll
  for (int i = 0; i < 4; ++i) {
    int c = tid + i * 256;          // 1024 float4 chunks
    int kr = c >> 4, col = (c & 15) * 4;
    *(float4*)&tile[kr][col] = *(const float4*)&w[(size_t)(k0 + kr) * 1024 + n0 + col];
  }
  __syncthreads();
#pragma unroll
  for (int i = 0; i < 2; ++i) {
    int c = tid + i * 256;          // 512 8xu16 chunks
    int nr = c >> 3, kc = (c & 7) * 8;
    __align__(16) u16 o[8];
#pragma unroll
    for (int j = 0; j < 8; ++j) o[j] = f2bf(tile[kc + j][nr]);
    *(uint4*)&wt[(size_t)(n0 + nr) * 1024 + k0 + kc] = *(const uint4*)o;
  }
}

// ---------------------------------------------------------------- GEMM core
// C[128x128] tile = A[m0..+128][K=1024] * Bt[n0..+128][K=1024]^T, bf16 MFMA.
// LDS tiles [128][32] bf16 (64B rows, 4x16B blocks), XOR-swizzled via
// pre-swizzled global source: block' = block ^ (row&3) ^ ((row>>2)&3).
DEV void gemm_mainloop(const u16* __restrict__ A, const u16* __restrict__ Bt,
                       int m0, int n0, u16* Asb, u16* Bsb, f32x4 (&acc)[4][4]) {
  const int tid = threadIdx.x;
  const int lane = tid & 63;
  const int wv = tid >> 6;
  const int wm = (wv >> 1) * 64, wn = (wv & 1) * 64;

#pragma unroll
  for (int i = 0; i < 4; ++i)
#pragma unroll
    for (int j = 0; j < 4; ++j) {
      f32x4 z = {0.f, 0.f, 0.f, 0.f};
      acc[i][j] = z;
    }

  const int c0 = wv * 64 + lane, c1 = c0 + 256;
  const int r0 = c0 >> 2, r1 = c1 >> 2;
  const int b0 = (c0 & 3) ^ (r0 & 3) ^ ((r0 >> 2) & 3);
  const int b1 = (c1 & 3) ^ (r1 & 3) ^ ((r1 >> 2) & 3);
  const u16* ga0 = A + (size_t)(m0 + r0) * 1024 + b0 * 8;
  const u16* ga1 = A + (size_t)(m0 + r1) * 1024 + b1 * 8;
  const u16* gb0 = Bt + (size_t)(n0 + r0) * 1024 + b0 * 8;
  const u16* gb1 = Bt + (size_t)(n0 + r1) * 1024 + b1 * 8;
  u16* la0 = Asb + (wv * 64) * 8;
  u16* la1 = Asb + (wv * 64 + 256) * 8;
  u16* lb0 = Bsb + (wv * 64) * 8;
  u16* lb1 = Bsb + (wv * 64 + 256) * 8;

  int aoff[4], boff[4];
#pragma unroll
  for (int f = 0; f < 4; ++f) {
    int ra = wm + f * 16 + (lane & 15);
    aoff[f] = ra * 32 + (((lane >> 4) ^ (ra & 3) ^ ((ra >> 2) & 3)) * 8);
    int rb = wn + f * 16 + (lane & 15);
    boff[f] = rb * 32 + (((lane >> 4) ^ (rb & 3) ^ ((rb >> 2) & 3)) * 8);
  }

  for (int kt = 0; kt < 32; ++kt) {
    const int k0 = kt * 32;
    gld16(ga0 + k0, la0);
    gld16(ga1 + k0, la1);
    gld16(gb0 + k0, lb0);
    gld16(gb1 + k0, lb1);
    __syncthreads();
    bf16x8 af[4], bfv[4];
#pragma unroll
    for (int f = 0; f < 4; ++f) af[f] = *(const bf16x8*)&Asb[aoff[f]];
#pragma unroll
    for (int f = 0; f < 4; ++f) bfv[f] = *(const bf16x8*)&Bsb[boff[f]];
#pragma unroll
    for (int i = 0; i < 4; ++i)
#pragma unroll
      for (int j = 0; j < 4; ++j)
        acc[i][j] = __builtin_amdgcn_mfma_f32_16x16x32_bf16(af[i], bfv[j], acc[i][j], 0, 0, 0);
    __syncthreads();
  }
}

// fused QKV projection: X[4096][1024]bf16 * Wt[1024][1024] -> Q/K/V [32][2048][64]bf16
__global__ __launch_bounds__(256) void k_gemm_qkv(
    const u16* __restrict__ X, const u16* __restrict__ Wq, const u16* __restrict__ Wk,
    const u16* __restrict__ Wv, u16* __restrict__ Q, u16* __restrict__ K,
    u16* __restrict__ V) {
  __shared__ __align__(16) u16 Asb[128 * 32];
  __shared__ __align__(16) u16 Bsb[128 * 32];
  const int nb = blockIdx.x, mb = blockIdx.y;
  const int proj = nb >> 3, n0 = (nb & 7) * 128;
  const u16* W = proj == 0 ? Wq : proj == 1 ? Wk : Wv;
  u16* Dst = proj == 0 ? Q : proj == 1 ? K : V;
  // fold 1/sqrt(64) * log2(e) into Q so attention can use exp2 directly
  const float scl = proj == 0 ? 0.125f * 1.4426950408889634f : 1.0f;
  f32x4 acc[4][4];
  gemm_mainloop(X, W, mb * 128, n0, Asb, Bsb, acc);
  const int lane = threadIdx.x & 63, wv = threadIdx.x >> 6;
  const int wm = (wv >> 1) * 64, wn = (wv & 1) * 64;
#pragma unroll
  for (int i = 0; i < 4; ++i)
#pragma unroll
    for (int j = 0; j < 4; ++j)
#pragma unroll
      for (int r = 0; r < 4; ++r) {
        int m = mb * 128 + wm + i * 16 + (lane >> 4) * 4 + r;   // global row (b*2048+s)
        int n = n0 + wn + j * 16 + (lane & 15);                 // 0..1023
        int b = m >> 11, s = m & 2047, h = n >> 6, d = n & 63;
        Dst[(size_t)((b * 16 + h) * 2048 + s) * 64 + d] = f2bf(acc[i][j][r] * scl);
      }
}

// output projection: AO[4096][1024]bf16 * WOt -> f32 out [4096][1024]
__global__ __launch_bounds__(256) void k_gemm_out(
    const u16* __restrict__ A, const u16* __restrict__ Wt, float* __restrict__ Out) {
  __shared__ __align__(16) u16 Asb[128 * 32];
  __shared__ __align__(16) u16 Bsb[128 * 32];
  const int nb = blockIdx.x, mb = blockIdx.y;
  f32x4 acc[4][4];
  gemm_mainloop(A, Wt, mb * 128, nb * 128, Asb, Bsb, acc);
  const int lane = threadIdx.x & 63, wv = threadIdx.x >> 6;
  const int wm = (wv >> 1) * 64, wn = (wv & 1) * 64;
#pragma unroll
  for (int i = 0; i < 4; ++i)
#pragma unroll
    for (int j = 0; j < 4; ++j)
#pragma unroll
      for (int r = 0; r < 4; ++r) {
        int m = mb * 128 + wm + i * 16 + (lane >> 4) * 4 + r;
        int n = nb * 128 + wn + j * 16 + (lane & 15);
        Out[(size_t)m * 1024 + n] = acc[i][j][r];
      }
}

// ---------------------------------------------------------------- V transpose
// V [32][2048][64] -> Vt [32][64][2048]
__global__ void k_transpose_v(const u16* __restrict__ V, u16* __restrict__ Vt) {
  __shared__ __align__(16) u16 t[64][80];
  const int bh = blockIdx.y, s0 = blockIdx.x * 64;
  const int tid = threadIdx.x;
#pragma unroll
  for (int i = 0; i < 2; ++i) {
    int c = tid + i * 256;
    int sr = c >> 3, dc = (c & 7) * 8;
    *(uint4*)&t[sr][dc] = *(const uint4*)&V[((size_t)bh * 2048 + s0 + sr) * 64 + dc];
  }
  __syncthreads();
#pragma unroll
  for (int i = 0; i < 2; ++i) {
    int c = tid + i * 256;
    int dr = c >> 3, sc = (c & 7) * 8;
    __align__(16) u16 o[8];
#pragma unroll
    for (int j = 0; j < 8; ++j) o[j] = t[sc + j][dr];
    *(uint4*)&Vt[((size_t)bh * 64 + dr) * 2048 + s0 + sc] = *(const uint4*)o;
  }
}

// ---------------------------------------------------------------- attention
// per block: one (b,h); TWO complementary 64-row q-tiles (j and 31-j) so every
// block does exactly 33 KV tiles regardless of causal position. 4 waves x 16
// rows. KVBLK=64, double-buffered K/V staging (stage t+1 while computing t).
__global__ __launch_bounds__(256) void k_attn(
    const u16* __restrict__ Qg, const u16* __restrict__ Kg,
    const u16* __restrict__ Vtg, u16* __restrict__ Og) {
  __shared__ __align__(16) u16 Ks[2][64 * 64];
  __shared__ __align__(16) u16 Vs[2][64 * 64];
  __shared__ __align__(16) u16 Ps[4][16 * 64];
  const int tid = threadIdx.x, lane = tid & 63, wv = tid >> 6;
  const int jpair = blockIdx.x, bh = blockIdx.y;
  const u16* Qb = Qg + (size_t)bh * 2048 * 64;
  const u16* Kb = Kg + (size_t)bh * 2048 * 64;
  const u16* Vb = Vtg + (size_t)bh * 64 * 2048;
  const int b = bh >> 4, h = bh & 15;

  // staging geometry: 512 chunks of 16B per 64x64 bf16 tile (128B rows, 8 blocks)
  const int c0 = wv * 64 + lane, c1 = c0 + 256;
  const int r0 = c0 >> 3, r1 = c1 >> 3;
  const int e0 = ((c0 & 7) ^ (r0 & 7)) * 8;
  const int e1 = ((c1 & 7) ^ (r1 & 7)) * 8;

#pragma unroll 1
  for (int pass = 0; pass < 2; ++pass) {
    const int qt = pass == 0 ? jpair : 31 - jpair;
    const int q0 = qt * 64;
    const int nt = qt + 1;

    // Q fragments in registers (scale * log2e already folded in)
    bf16x8 qf[2];
#pragma unroll
    for (int kf = 0; kf < 2; ++kf)
      qf[kf] = *(const bf16x8*)&Qb[(size_t)(q0 + wv * 16 + (lane & 15)) * 64 +
                                   kf * 32 + (lane >> 4) * 8];

    f32x4 ao[4];
    float m_run[4], l_run[4];
#pragma unroll
    for (int df = 0; df < 4; ++df) {
      f32x4 z = {0.f, 0.f, 0.f, 0.f};
      ao[df] = z;
    }
#pragma unroll
    for (int r = 0; r < 4; ++r) { m_run[r] = -1e30f; l_run[r] = 0.f; }

    // prologue: stage tile 0 into buf 0
    gld16(Kb + (size_t)(0 + r0) * 64 + e0, &Ks[0][wv * 512]);
    gld16(Kb + (size_t)(0 + r1) * 64 + e1, &Ks[0][wv * 512 + 2048]);
    gld16(Vb + (size_t)r0 * 2048 + 0 + e0, &Vs[0][wv * 512]);
    gld16(Vb + (size_t)r1 * 2048 + 0 + e1, &Vs[0][wv * 512 + 2048]);
    __syncthreads();

    int cur = 0;
#pragma unroll 1
    for (int t = 0; t < nt; ++t) {
      const int kv0 = t * 64;
      // stage next tile into the other buffer (overlaps with compute below)
      if (t + 1 < nt) {
        const int kn = kv0 + 64;
        gld16(Kb + (size_t)(kn + r0) * 64 + e0, &Ks[cur ^ 1][wv * 512]);
        gld16(Kb + (size_t)(kn + r1) * 64 + e1, &Ks[cur ^ 1][wv * 512 + 2048]);
        gld16(Vb + (size_t)r0 * 2048 + kn + e0, &Vs[cur ^ 1][wv * 512]);
        gld16(Vb + (size_t)r1 * 2048 + kn + e1, &Vs[cur ^ 1][wv * 512 + 2048]);
      }

      // QK^T
      bf16x8 kfr[4][2];
#pragma unroll
      for (int cf = 0; cf < 4; ++cf)
#pragma unroll
        for (int kf = 0; kf < 2; ++kf) {
          int row = cf * 16 + (lane & 15);
          int blk = ((kf * 4 + (lane >> 4)) ^ (row & 7)) * 8;
          kfr[cf][kf] = *(const bf16x8*)&Ks[cur][row * 64 + blk];
        }
      f32x4 sc[4];
#pragma unroll
      for (int cf = 0; cf < 4; ++cf) {
        f32x4 z = {0.f, 0.f, 0.f, 0.f};
        sc[cf] = z;
#pragma unroll
        for (int kf = 0; kf < 2; ++kf)
          sc[cf] = __builtin_amdgcn_mfma_f32_16x16x32_bf16(qf[kf], kfr[cf][kf],
                                                           sc[cf], 0, 0, 0);
      }

      // causal mask (only the diagonal tile needs it)
      if (kv0 + 63 > q0 + 15 + wv * 16 || kv0 + 63 > q0 + 48) {
#pragma unroll
        for (int cf = 0; cf < 4; ++cf)
#pragma unroll
          for (int r = 0; r < 4; ++r) {
            int qq = q0 + wv * 16 + (lane >> 4) * 4 + r;
            int kk = kv0 + cf * 16 + (lane & 15);
            if (kk > qq) sc[cf][r] = -1e30f;
          }
      }

      // online softmax (scores are in log2 domain; exp2)
      float mnew[4], sclf[4], psum[4];
#pragma unroll
      for (int r = 0; r < 4; ++r) {
        float mx = fmaxf(fmaxf(sc[0][r], sc[1][r]), fmaxf(sc[2][r], sc[3][r]));
        mx = fmaxf(mx, __shfl_xor(mx, 1));
        mx = fmaxf(mx, __shfl_xor(mx, 2));
        mx = fmaxf(mx, __shfl_xor(mx, 4));
        mx = fmaxf(mx, __shfl_xor(mx, 8));
        mnew[r] = fmaxf(m_run[r], mx);
        sclf[r] = __builtin_amdgcn_exp2f(m_run[r] - mnew[r]);
        m_run[r] = mnew[r];
        psum[r] = 0.f;
      }
#pragma unroll
      for (int cf = 0; cf < 4; ++cf)
#pragma unroll
        for (int r = 0; r < 4; ++r) {
          float p = __builtin_amdgcn_exp2f(sc[cf][r] - mnew[r]);
          sc[cf][r] = p;
          psum[r] += p;
        }
#pragma unroll
      for (int r = 0; r < 4; ++r) {
        psum[r] += __shfl_xor(psum[r], 1);
        psum[r] += __shfl_xor(psum[r], 2);
        psum[r] += __shfl_xor(psum[r], 4);
        psum[r] += __shfl_xor(psum[r], 8);
        l_run[r] = l_run[r] * sclf[r] + psum[r];
      }
#pragma unroll
      for (int df = 0; df < 4; ++df)
#pragma unroll
        for (int r = 0; r < 4; ++r) ao[df][r] *= sclf[r];

      // P -> bf16 -> per-wave swizzled LDS buffer
#pragma unroll
      for (int cf = 0; cf < 4; ++cf)
#pragma unroll
        for (int r = 0; r < 4; ++r) {
          int rl = (lane >> 4) * 4 + r;
          int col = cf * 16 + (lane & 15);
          Ps[wv][rl * 64 + (col ^ ((rl & 7) << 3))] = f2bf(sc[cf][r]);
        }
      asm volatile("s_waitcnt lgkmcnt(0)" ::: "memory");

      // PV
      bf16x8 pf[2], vfr[4][2];
#pragma unroll
      for (int k2 = 0; k2 < 2; ++k2) {
        int row = lane & 15;
        pf[k2] = *(const bf16x8*)&Ps[wv][row * 64 +
                   ((k2 * 32 + (lane >> 4) * 8) ^ ((row & 7) << 3))];
      }
#pragma unroll
      for (int df = 0; df < 4; ++df)
#pragma unroll
        for (int k2 = 0; k2 < 2; ++k2) {
          int row = df * 16 + (lane & 15);
          int blk = ((k2 * 4 + (lane >> 4)) ^ (row & 7)) * 8;
          vfr[df][k2] = *(const bf16x8*)&Vs[cur][row * 64 + blk];
        }
#pragma unroll
      for (int df = 0; df < 4; ++df)
#pragma unroll
        for (int k2 = 0; k2 < 2; ++k2)
          ao[df] = __builtin_amdgcn_mfma_f32_16x16x32_bf16(pf[k2], vfr[df][k2],
                                                           ao[df], 0, 0, 0);
      // implicit vmcnt(0)+lgkmcnt(0) drain: next tile resident, reads done
      __syncthreads();
      cur ^= 1;
    }

    // epilogue: write [B][S][H*64] bf16 for the output projection
#pragma unroll
    for (int df = 0; df < 4; ++df)
#pragma unroll
      for (int r = 0; r < 4; ++r) {
        int s = q0 + wv * 16 + (lane >> 4) * 4 + r;
        int d = df * 16 + (lane & 15);
        float v = ao[df][r] / l_run[r];
        Og[((size_t)(b * 2048 + s)) * 1024 + h * 64 + d] = f2bf(v);
      }
    __syncthreads();   // LDS reuse safety between passes
  }
}

// ---------------------------------------------------------------- launch
extern "C" void kernel_launch(void* const* d_in, const int* in_sizes, int n_in,
                              void* d_out, int out_size, void* d_ws, size_t ws_size,
                              hipStream_t stream) {
  const float* x = (const float*)d_in[0];
  // d_in[1] = causal mask (known layout; not needed on device)
  const float* wq = (const float*)d_in[2];
  const float* wk = (const float*)d_in[3];
  const float* wv = (const float*)d_in[4];
  const float* wo = (const float*)d_in[5];

  char* ws = (char*)d_ws;
  u16* xb  = (u16*)(ws);                                   // 8 MiB  x bf16 [4096][1024]
  u16* wqt = (u16*)(ws + 8388608);                         // 2 MiB each, [N][K] bf16
  u16* wkt = (u16*)(ws + 8388608 + 2097152);
  u16* wvt = (u16*)(ws + 8388608 + 2 * 2097152);
  u16* wot = (u16*)(ws + 8388608 + 3 * 2097152);
  u16* qb  = (u16*)(ws + 16777216);                        // [32][2048][64] bf16
  u16* kb  = (u16*)(ws + 16777216 + 8388608);
  u16* vb  = (u16*)(ws + 16777216 + 2 * 8388608);
  u16* vt  = (u16*)(ws + 16777216 + 3 * 8388608);          // [32][64][2048]
  u16* ao  = (u16*)(ws + 16777216 + 4 * 8388608);          // [4096][1024] bf16

  k_cvt_x<<<dim3(2048), dim3(256), 0, stream>>>(x, xb);
  k_cvt_w<<<dim3(16, 16, 4), dim3(256), 0, stream>>>(wq, wk, wv, wo, wqt, wkt, wvt, wot);
  k_gemm_qkv<<<dim3(24, 32), dim3(256), 0, stream>>>(xb, wqt, wkt, wvt, qb, kb, vb);
  k_transpose_v<<<dim3(32, 32), dim3(256), 0, stream>>>(vb, vt);
  k_attn<<<dim3(16, 32), dim3(256), 0, stream>>>(qb, kb, vt, ao);
  k_gemm_out<<<dim3(8, 32), dim3(256), 0, stream>>>(ao, wot, (float*)d_out);
}

// Round 3
// 128.795 us; speedup vs baseline: 1.4894x; 1.1658x over previous
//
#include <hip/hip_runtime.h>
#include <stdint.h>

using u16 = unsigned short;
using u32 = unsigned int;
using u64 = unsigned long long;

typedef float f32x4 __attribute__((ext_vector_type(4)));
typedef __bf16 bf16x8 __attribute__((ext_vector_type(8)));

#define DEV static __device__ __forceinline__

// f32 -> bf16 round-to-nearest-even
DEV u16 f2bf(float f) {
  u32 u = __float_as_uint(f);
  u += 0x7FFFu + ((u >> 16) & 1u);
  return (u16)(u >> 16);
}

// async global->LDS, 16B per lane. LDS dest = wave-uniform base + lane*16.
DEV void gld16(const void* g, void* l) {
  __builtin_amdgcn_global_load_lds((__attribute__((address_space(1))) void*)g,
                                   (__attribute__((address_space(3))) void*)l,
                                   16, 0, 0);
}

// ---------------------------------------------------------------- converts
__global__ void k_cvt_x(const float* __restrict__ x, u16* __restrict__ xb) {
  int i = (blockIdx.x * 256 + threadIdx.x) * 8;
  float4 a = *(const float4*)&x[i];
  float4 b = *(const float4*)&x[i + 4];
  __align__(16) u16 o[8];
  o[0] = f2bf(a.x); o[1] = f2bf(a.y); o[2] = f2bf(a.z); o[3] = f2bf(a.w);
  o[4] = f2bf(b.x); o[5] = f2bf(b.y); o[6] = f2bf(b.z); o[7] = f2bf(b.w);
  *(uint4*)&xb[i] = *(const uint4*)o;
}

// convert f32 [K=1024][N=1024] weight -> bf16 transposed [N][K]
__global__ void k_cvt_w(const float* __restrict__ w0, const float* __restrict__ w1,
                        const float* __restrict__ w2, const float* __restrict__ w3,
                        u16* __restrict__ t0, u16* __restrict__ t1,
                        u16* __restrict__ t2, u16* __restrict__ t3) {
  const float* w = blockIdx.z == 0 ? w0 : blockIdx.z == 1 ? w1 : blockIdx.z == 2 ? w2 : w3;
  u16* wt       = blockIdx.z == 0 ? t0 : blockIdx.z == 1 ? t1 : blockIdx.z == 2 ? t2 : t3;
  __shared__ __align__(16) float tile[64][68];
  const int tid = threadIdx.x;
  const int k0 = blockIdx.x * 64, n0 = blockIdx.y * 64;
#pragma unroll
  for (int i = 0; i < 4; ++i) {
    int c = tid + i * 256;          // 1024 float4 chunks
    int kr = c >> 4, col = (c & 15) * 4;
    *(float4*)&tile[kr][col] = *(const float4*)&w[(size_t)(k0 + kr) * 1024 + n0 + col];
  }
  __syncthreads();
#pragma unroll
  for (int i = 0; i < 2; ++i) {
    int c = tid + i * 256;          // 512 8xu16 chunks
    int nr = c >> 3, kc = (c & 7) * 8;
    __align__(16) u16 o[8];
#pragma unroll
    for (int j = 0; j < 8; ++j) o[j] = f2bf(tile[kc + j][nr]);
    *(uint4*)&wt[(size_t)(n0 + nr) * 1024 + k0 + kc] = *(const uint4*)o;
  }
}

// ---------------------------------------------------------------- GEMM core
DEV void gemm_mainloop(const u16* __restrict__ A, const u16* __restrict__ Bt,
                       int m0, int n0, u16* Asb, u16* Bsb, f32x4 (&acc)[4][4]) {
  const int tid = threadIdx.x;
  const int lane = tid & 63;
  const int wv = tid >> 6;
  const int wm = (wv >> 1) * 64, wn = (wv & 1) * 64;

#pragma unroll
  for (int i = 0; i < 4; ++i)
#pragma unroll
    for (int j = 0; j < 4; ++j) {
      f32x4 z = {0.f, 0.f, 0.f, 0.f};
      acc[i][j] = z;
    }

  const int c0 = wv * 64 + lane, c1 = c0 + 256;
  const int r0 = c0 >> 2, r1 = c1 >> 2;
  const int b0 = (c0 & 3) ^ (r0 & 3) ^ ((r0 >> 2) & 3);
  const int b1 = (c1 & 3) ^ (r1 & 3) ^ ((r1 >> 2) & 3);
  const u16* ga0 = A + (size_t)(m0 + r0) * 1024 + b0 * 8;
  const u16* ga1 = A + (size_t)(m0 + r1) * 1024 + b1 * 8;
  const u16* gb0 = Bt + (size_t)(n0 + r0) * 1024 + b0 * 8;
  const u16* gb1 = Bt + (size_t)(n0 + r1) * 1024 + b1 * 8;
  u16* la0 = Asb + (wv * 64) * 8;
  u16* la1 = Asb + (wv * 64 + 256) * 8;
  u16* lb0 = Bsb + (wv * 64) * 8;
  u16* lb1 = Bsb + (wv * 64 + 256) * 8;

  int aoff[4], boff[4];
#pragma unroll
  for (int f = 0; f < 4; ++f) {
    int ra = wm + f * 16 + (lane & 15);
    aoff[f] = ra * 32 + (((lane >> 4) ^ (ra & 3) ^ ((ra >> 2) & 3)) * 8);
    int rb = wn + f * 16 + (lane & 15);
    boff[f] = rb * 32 + (((lane >> 4) ^ (rb & 3) ^ ((rb >> 2) & 3)) * 8);
  }

  for (int kt = 0; kt < 32; ++kt) {
    const int k0 = kt * 32;
    gld16(ga0 + k0, la0);
    gld16(ga1 + k0, la1);
    gld16(gb0 + k0, lb0);
    gld16(gb1 + k0, lb1);
    __syncthreads();
    bf16x8 af[4], bfv[4];
#pragma unroll
    for (int f = 0; f < 4; ++f) af[f] = *(const bf16x8*)&Asb[aoff[f]];
#pragma unroll
    for (int f = 0; f < 4; ++f) bfv[f] = *(const bf16x8*)&Bsb[boff[f]];
#pragma unroll
    for (int i = 0; i < 4; ++i)
#pragma unroll
      for (int j = 0; j < 4; ++j)
        acc[i][j] = __builtin_amdgcn_mfma_f32_16x16x32_bf16(af[i], bfv[j], acc[i][j], 0, 0, 0);
    __syncthreads();
  }
}

// fused QKV projection: X[4096][1024]bf16 * Wt[1024][1024] -> Q/K/V [32][2048][64]bf16
__global__ __launch_bounds__(256) void k_gemm_qkv(
    const u16* __restrict__ X, const u16* __restrict__ Wq, const u16* __restrict__ Wk,
    const u16* __restrict__ Wv, u16* __restrict__ Q, u16* __restrict__ K,
    u16* __restrict__ V) {
  __shared__ __align__(16) u16 Asb[128 * 32];
  __shared__ __align__(16) u16 Bsb[128 * 32];
  const int nb = blockIdx.x, mb = blockIdx.y;
  const int proj = nb >> 3, n0 = (nb & 7) * 128;
  const u16* W = proj == 0 ? Wq : proj == 1 ? Wk : Wv;
  u16* Dst = proj == 0 ? Q : proj == 1 ? K : V;
  // fold 1/sqrt(64) * log2(e) into Q so attention can use exp2 directly
  const float scl = proj == 0 ? 0.125f * 1.4426950408889634f : 1.0f;
  f32x4 acc[4][4];
  gemm_mainloop(X, W, mb * 128, n0, Asb, Bsb, acc);
  const int lane = threadIdx.x & 63, wv = threadIdx.x >> 6;
  const int wm = (wv >> 1) * 64, wn = (wv & 1) * 64;
#pragma unroll
  for (int i = 0; i < 4; ++i)
#pragma unroll
    for (int j = 0; j < 4; ++j)
#pragma unroll
      for (int r = 0; r < 4; ++r) {
        int m = mb * 128 + wm + i * 16 + (lane >> 4) * 4 + r;   // global row (b*2048+s)
        int n = n0 + wn + j * 16 + (lane & 15);                 // 0..1023
        int b = m >> 11, s = m & 2047, h = n >> 6, d = n & 63;
        Dst[(size_t)((b * 16 + h) * 2048 + s) * 64 + d] = f2bf(acc[i][j][r] * scl);
      }
}

// output projection: AO[4096][1024]bf16 * WOt -> f32 out [4096][1024]
__global__ __launch_bounds__(256) void k_gemm_out(
    const u16* __restrict__ A, const u16* __restrict__ Wt, float* __restrict__ Out) {
  __shared__ __align__(16) u16 Asb[128 * 32];
  __shared__ __align__(16) u16 Bsb[128 * 32];
  const int nb = blockIdx.x, mb = blockIdx.y;
  f32x4 acc[4][4];
  gemm_mainloop(A, Wt, mb * 128, nb * 128, Asb, Bsb, acc);
  const int lane = threadIdx.x & 63, wv = threadIdx.x >> 6;
  const int wm = (wv >> 1) * 64, wn = (wv & 1) * 64;
#pragma unroll
  for (int i = 0; i < 4; ++i)
#pragma unroll
    for (int j = 0; j < 4; ++j)
#pragma unroll
      for (int r = 0; r < 4; ++r) {
        int m = mb * 128 + wm + i * 16 + (lane >> 4) * 4 + r;
        int n = nb * 128 + wn + j * 16 + (lane & 15);
        Out[(size_t)m * 1024 + n] = acc[i][j][r];
      }
}

// ---------------------------------------------------------------- V transpose
// V [32][2048][64] -> Vt' [32][64][2048] with sigma k-permutation applied
// within each 64-column block: sigma(k): bits [b5b4b3b2b1b0] -> [b4b3b2|b5|b1b0]
// i.e. k' = b4*32 + b3*16 + b2*8 + b5*4 + (k&3). This matches the in-register
// P fragment order produced by the swapped QK^T in k_attn (PV contracts over
// permuted k on both sides, so the result is unchanged).
__global__ void k_transpose_v(const u16* __restrict__ V, u16* __restrict__ Vt) {
  __shared__ __align__(16) u16 t[64][80];
  const int bh = blockIdx.y, s0 = blockIdx.x * 64;
  const int tid = threadIdx.x;
#pragma unroll
  for (int i = 0; i < 2; ++i) {
    int c = tid + i * 256;
    int sr = c >> 3, dc = (c & 7) * 8;
    *(uint4*)&t[sr][dc] = *(const uint4*)&V[((size_t)bh * 2048 + s0 + sr) * 64 + dc];
  }
  __syncthreads();
#pragma unroll
  for (int i = 0; i < 2; ++i) {
    int c = tid + i * 256;
    int dr = c >> 3, c7 = c & 7;
    // source s-indices: 8*c7 + j, j=0..7
    __align__(8) u16 o[8];
#pragma unroll
    for (int j = 0; j < 8; ++j) o[j] = t[c7 * 8 + j][dr];
    // sigma: base' = b4*32 + b3*16 + b5*4 ; col = base' + (j>>2)*8 + (j&3)
    int bp = ((c7 >> 1) & 1) * 32 + (c7 & 1) * 16 + ((c7 >> 2) & 1) * 4;
    u16* row = &Vt[((size_t)bh * 64 + dr) * 2048 + s0];
    *(u64*)&row[bp]     = *(const u64*)&o[0];
    *(u64*)&row[bp + 8] = *(const u64*)&o[4];
  }
}

// ---------------------------------------------------------------- attention
// per block: one (b,h); TWO complementary 64-row q-tiles (j and 31-j) so every
// block does exactly 33 KV tiles. 4 waves x 16 rows. KVBLK=64, double-buffered.
// SWAPPED QK^T: sc = mfma(K_frag, Q_frag) = S^T, so each lane owns one q-row
// (q = lane&15) and 16 of the 64 k-values -> softmax is in-lane + 2 shuffles,
// and P feeds PV's A-fragments entirely in-register (via the sigma permutation
// baked into Vt').
__global__ __launch_bounds__(256) void k_attn(
    const u16* __restrict__ Qg, const u16* __restrict__ Kg,
    const u16* __restrict__ Vtg, u16* __restrict__ Og) {
  __shared__ __align__(16) u16 Ks[2][64 * 64];
  __shared__ __align__(16) u16 Vs[2][64 * 64];
  const int tid = threadIdx.x, lane = tid & 63, wv = tid >> 6;
  const int lo = lane & 15, hi = lane >> 4;
  const int jpair = blockIdx.x, bh = blockIdx.y;
  const u16* Qb = Qg + (size_t)bh * 2048 * 64;
  const u16* Kb = Kg + (size_t)bh * 2048 * 64;
  const u16* Vb = Vtg + (size_t)bh * 64 * 2048;
  const int b = bh >> 4, h = bh & 15;

  // staging geometry: 512 chunks of 16B per 64x64 bf16 tile (128B rows, 8 blocks)
  const int c0 = wv * 64 + lane, c1 = c0 + 256;
  const int r0 = c0 >> 3, r1 = c1 >> 3;
  const int e0 = ((c0 & 7) ^ (r0 & 7)) * 8;
  const int e1 = ((c1 & 7) ^ (r1 & 7)) * 8;

#pragma unroll 1
  for (int pass = 0; pass < 2; ++pass) {
    const int qt = pass == 0 ? jpair : 31 - jpair;
    const int q0 = qt * 64;
    const int nt = qt + 1;
    const int qq = q0 + wv * 16 + lo;     // this lane's q-row

    // Q fragments (scale * log2e folded in); used as B-operand of swapped QK^T
    bf16x8 qf[2];
#pragma unroll
    for (int kf = 0; kf < 2; ++kf)
      qf[kf] = *(const bf16x8*)&Qb[(size_t)(q0 + wv * 16 + lo) * 64 + kf * 32 + hi * 8];

    f32x4 ao[4];
#pragma unroll
    for (int df = 0; df < 4; ++df) {
      f32x4 z = {0.f, 0.f, 0.f, 0.f};
      ao[df] = z;
    }
    float m_run = -1e30f, l_run = 0.f;

    // prologue: stage tile 0 into buf 0
    gld16(Kb + (size_t)r0 * 64 + e0, &Ks[0][wv * 512]);
    gld16(Kb + (size_t)r1 * 64 + e1, &Ks[0][wv * 512 + 2048]);
    gld16(Vb + (size_t)r0 * 2048 + e0, &Vs[0][wv * 512]);
    gld16(Vb + (size_t)r1 * 2048 + e1, &Vs[0][wv * 512 + 2048]);
    __syncthreads();

    int cur = 0;
#pragma unroll 1
    for (int t = 0; t < nt; ++t) {
      const int kv0 = t * 64;
      if (t + 1 < nt) {
        const int kn = kv0 + 64;
        gld16(Kb + (size_t)(kn + r0) * 64 + e0, &Ks[cur ^ 1][wv * 512]);
        gld16(Kb + (size_t)(kn + r1) * 64 + e1, &Ks[cur ^ 1][wv * 512 + 2048]);
        gld16(Vb + (size_t)r0 * 2048 + kn + e0, &Vs[cur ^ 1][wv * 512]);
        gld16(Vb + (size_t)r1 * 2048 + kn + e1, &Vs[cur ^ 1][wv * 512 + 2048]);
      }

      // swapped QK^T: sc[cf] = S^T tile; lane holds q=lo, k=kv0+cf*16+hi*4+r
      f32x4 sc[4];
#pragma unroll
      for (int cf = 0; cf < 4; ++cf) {
        f32x4 z = {0.f, 0.f, 0.f, 0.f};
        sc[cf] = z;
#pragma unroll
        for (int kf = 0; kf < 2; ++kf) {
          int row = cf * 16 + lo;
          int blk = ((kf * 4 + hi) ^ (row & 7)) * 8;
          bf16x8 kfr = *(const bf16x8*)&Ks[cur][row * 64 + blk];
          sc[cf] = __builtin_amdgcn_mfma_f32_16x16x32_bf16(kfr, qf[kf], sc[cf], 0, 0, 0);
        }
      }

      // causal mask: only the diagonal (last) tile
      if (t == nt - 1) {
#pragma unroll
        for (int cf = 0; cf < 4; ++cf)
#pragma unroll
          for (int r = 0; r < 4; ++r) {
            int kk = kv0 + cf * 16 + hi * 4 + r;
            if (kk > qq) sc[cf][r] = -1e30f;
          }
      }

      // in-lane row max (16 values) + 2 cross-lane shuffles
      float mx0 = fmaxf(fmaxf(sc[0][0], sc[0][1]), fmaxf(sc[0][2], sc[0][3]));
      float mx1 = fmaxf(fmaxf(sc[1][0], sc[1][1]), fmaxf(sc[1][2], sc[1][3]));
      float mx2 = fmaxf(fmaxf(sc[2][0], sc[2][1]), fmaxf(sc[2][2], sc[2][3]));
      float mx3 = fmaxf(fmaxf(sc[3][0], sc[3][1]), fmaxf(sc[3][2], sc[3][3]));
      float mx = fmaxf(fmaxf(mx0, mx1), fmaxf(mx2, mx3));
      mx = fmaxf(mx, __shfl_xor(mx, 16));
      mx = fmaxf(mx, __shfl_xor(mx, 32));

      // defer-max: rescale only when the max grew by > 8 (log2 units)
      if (__any(mx > m_run + 8.0f)) {
        float mnew = fmaxf(m_run, mx);
        float sclf = __builtin_amdgcn_exp2f(m_run - mnew);
        const int base = lane & 48;
#pragma unroll
        for (int r = 0; r < 4; ++r) {
          float s_r = __shfl(sclf, base + hi * 4 + r);
#pragma unroll
          for (int df = 0; df < 4; ++df) ao[df][r] *= s_r;
        }
        l_run *= sclf;
        m_run = mnew;
      }

      // P = exp2(sc - m_run), packed in-register into PV A-fragments.
      // sigma maps k=cf*16+hi*4+r -> pa[cf&1][(cf>>1)*4+r]
      float pp[4];
      bf16x8 pa0, pa1;
#pragma unroll
      for (int cf = 0; cf < 4; ++cf) {
        float p0 = __builtin_amdgcn_exp2f(sc[cf][0] - m_run);
        float p1 = __builtin_amdgcn_exp2f(sc[cf][1] - m_run);
        float p2 = __builtin_amdgcn_exp2f(sc[cf][2] - m_run);
        float p3 = __builtin_amdgcn_exp2f(sc[cf][3] - m_run);
        pp[cf] = (p0 + p1) + (p2 + p3);
        bf16x8& pa = (cf & 1) ? pa1 : pa0;
        int j = (cf >> 1) * 4;
        pa[j] = (__bf16)p0; pa[j + 1] = (__bf16)p1;
        pa[j + 2] = (__bf16)p2; pa[j + 3] = (__bf16)p3;
      }
      float psum = (pp[0] + pp[1]) + (pp[2] + pp[3]);
      psum += __shfl_xor(psum, 16);
      psum += __shfl_xor(psum, 32);
      l_run += psum;

      // PV: ao[df] += pa[kf] * V'[k'][d]
#pragma unroll
      for (int df = 0; df < 4; ++df) {
#pragma unroll
        for (int kf = 0; kf < 2; ++kf) {
          int row = df * 16 + lo;
          int blk = ((kf * 4 + hi) ^ (row & 7)) * 8;
          bf16x8 vfr = *(const bf16x8*)&Vs[cur][row * 64 + blk];
          ao[df] = __builtin_amdgcn_mfma_f32_16x16x32_bf16(kf == 0 ? pa0 : pa1, vfr,
                                                           ao[df], 0, 0, 0);
        }
      }
      // implicit vmcnt(0)+lgkmcnt(0) drain: next tile resident, reads done
      __syncthreads();
      cur ^= 1;
    }

    // epilogue: ao rows are q-offsets hi*4+r; fetch each row's l via shuffle
    float linv[4];
    const int base = lane & 48;
#pragma unroll
    for (int r = 0; r < 4; ++r) {
      float l_r = __shfl(l_run, base + hi * 4 + r);
      linv[r] = 1.0f / l_r;
    }
#pragma unroll
    for (int df = 0; df < 4; ++df)
#pragma unroll
      for (int r = 0; r < 4; ++r) {
        int s = q0 + wv * 16 + hi * 4 + r;
        int d = df * 16 + lo;
        Og[((size_t)(b * 2048 + s)) * 1024 + h * 64 + d] = f2bf(ao[df][r] * linv[r]);
      }
    __syncthreads();   // LDS reuse safety between passes
  }
}

// ---------------------------------------------------------------- launch
extern "C" void kernel_launch(void* const* d_in, const int* in_sizes, int n_in,
                              void* d_out, int out_size, void* d_ws, size_t ws_size,
                              hipStream_t stream) {
  const float* x = (const float*)d_in[0];
  const float* wq = (const float*)d_in[2];
  const float* wk = (const float*)d_in[3];
  const float* wv = (const float*)d_in[4];
  const float* wo = (const float*)d_in[5];

  char* ws = (char*)d_ws;
  u16* xb  = (u16*)(ws);                                   // 8 MiB  x bf16 [4096][1024]
  u16* wqt = (u16*)(ws + 8388608);                         // 2 MiB each, [N][K] bf16
  u16* wkt = (u16*)(ws + 8388608 + 2097152);
  u16* wvt = (u16*)(ws + 8388608 + 2 * 2097152);
  u16* wot = (u16*)(ws + 8388608 + 3 * 2097152);
  u16* qb  = (u16*)(ws + 16777216);                        // [32][2048][64] bf16
  u16* kb  = (u16*)(ws + 16777216 + 8388608);
  u16* vb  = (u16*)(ws + 16777216 + 2 * 8388608);
  u16* vt  = (u16*)(ws + 16777216 + 3 * 8388608);          // [32][64][2048] (sigma-permuted)
  u16* ao  = (u16*)(ws + 16777216 + 4 * 8388608);          // [4096][1024] bf16

  k_cvt_x<<<dim3(2048), dim3(256), 0, stream>>>(x, xb);
  k_cvt_w<<<dim3(16, 16, 4), dim3(256), 0, stream>>>(wq, wk, wv, wo, wqt, wkt, wvt, wot);
  k_gemm_qkv<<<dim3(24, 32), dim3(256), 0, stream>>>(xb, wqt, wkt, wvt, qb, kb, vb);
  k_transpose_v<<<dim3(32, 32), dim3(256), 0, stream>>>(vb, vt);
  k_attn<<<dim3(16, 32), dim3(256), 0, stream>>>(qb, kb, vt, ao);
  k_gemm_out<<<dim3(8, 32), dim3(256), 0, stream>>>(ao, wot, (float*)d_out);
}